// Round 10
// baseline (102.337 us; speedup 1.0000x reference)
//
#include <hip/hip_runtime.h>
#include <math.h>

typedef __attribute__((ext_vector_type(8))) short short8v;   // 8 bf16 bits
typedef __attribute__((ext_vector_type(4))) float f32x4;     // 16x16 MFMA acc

__device__ __forceinline__ unsigned short f2bf(float x) {
    union { float f; unsigned u; } v; v.f = x;
    unsigned r = v.u + 0x7FFF + ((v.u >> 16) & 1);   // RNE
    return (unsigned short)(r >> 16);
}
__device__ __forceinline__ float bf2f(unsigned short u) {
    union { unsigned u; float f; } v; v.u = ((unsigned)u) << 16;
    return v.f;
}
__device__ __forceinline__ unsigned pack2bf(float a, float b) {
    return (unsigned)f2bf(a) | ((unsigned)f2bf(b) << 16);
}
__device__ __forceinline__ float fast_tanh(float x) {
    float e = __expf(2.0f * x);
    return 1.0f - 2.0f / (e + 1.0f);
}
__device__ __host__ __forceinline__ int sigma_perm(int ct, int p) {
    return 32 * (ct >> 1) + 8 * (p >> 2) + 4 * (ct & 1) + (p & 3);
}

// d_ws layout (bytes):
//   [0, 4096)       A     f32  [64][16]            (fallback path only)
//   [4096, 12288)   W1P   bf16 [8 ct][16 row][32 k]  k>=16 ZERO, sigma rows
//   [12288, 45056)  W2P   bf16 [8 ct][16 row][128 k] sigma rows
//   [45056, 49152)  W3T   bf16 [16 col][128 k]
//   [49152, 57344)  MP    bf16 [8 ct][16 row][32 k]  k>=16 ZERO (epilogue matrix)
//   [57344, 57344 + B*64)  LS buffer f32 [B][16]
#define WS_A    0
#define WS_W1   4096
#define WS_W2   12288
#define WS_W3   45056
#define WS_MP   49152
#define WS_LS   57344

// ---------------------------------------------------------------------------
// Prep: one block, 256 threads. A-build proven; adds MP (epilogue matrix).
// ---------------------------------------------------------------------------
__global__ __launch_bounds__(256) void ce_prep_kernel(
    const int* __restrict__ pilot_pos,
    const float* __restrict__ decay_param,
    const float* __restrict__ window_logits,
    const float* __restrict__ W1, const float* __restrict__ W2,
    const float* __restrict__ W3,
    char* __restrict__ ws)
{
    __shared__ float win[8], Gr[64], Gi[64], wln[64], wrn[64];
    __shared__ int lefts[64], pos[8];
    __shared__ float sA[64 * 16];
    int t = threadIdx.x;
    if (t < 8) {
        pos[t] = pilot_pos[t];
        win[t] = 1.0f / (1.0f + expf(-window_logits[t]));
    }
    __syncthreads();
    float decay = log1pf(expf(decay_param[0]));
    if (t < 64) {
        float gr = 0.f, gi = 0.f;
        #pragma unroll
        for (int n = 0; n < 8; ++n) {
            float ang = 6.283185307179586f * (float)(n * t) * (1.0f / 64.0f);
            gr += win[n] * cosf(ang);
            gi += win[n] * sinf(ang);
        }
        Gr[t] = gr * (1.0f / 64.0f);
        Gi[t] = gi * (1.0f / 64.0f);
        int lft = 0;
        #pragma unroll
        for (int p = 1; p < 8; ++p) if (pos[p] <= t) lft = p;
        if (lft > 6) lft = 6;
        float x0 = (float)pos[lft], x1 = (float)pos[lft + 1], fi = (float)t;
        float wl = expf(-decay * fabsf(fi - x0));
        float wr = expf(-decay * fabsf(x1 - fi));
        float wsum = wl + wr + 1e-12f;
        lefts[t] = lft; wln[t] = wl / wsum; wrn[t] = wr / wsum;
    }
    __syncthreads();
    if (t < 64) {
        float ar[8], ai[8];
        for (int p = 0; p < 8; ++p) { ar[p] = 0.f; ai[p] = 0.f; }
        for (int i = 0; i < 64; ++i) {
            int d = (i - t) & 63;
            float gr = Gr[d], gi = Gi[d];
            int lft = lefts[i];
            float wa = wln[i], wb = wrn[i];
            ar[lft]     += wa * gr;  ai[lft]     += wa * gi;
            ar[lft + 1] += wb * gr;  ai[lft + 1] += wb * gi;
        }
        float* A = (float*)(ws + WS_A);
        for (int p = 0; p < 8; ++p) {
            A[t * 16 + 2 * p]     = ar[p];
            A[t * 16 + 2 * p + 1] = ai[p];
            sA[t * 16 + 2 * p]     = ar[p];
            sA[t * 16 + 2 * p + 1] = ai[p];
        }
    }
    __syncthreads();
    // MP: [ct][jl][32 k]; j=ct*16+jl, m=j>>1, s=j&1, p=k>>1, u=k&1
    //   s==0: u==0 -> Ar[m][p], u==1 -> -Ai[m][p]
    //   s==1: u==0 -> Ai[m][p], u==1 ->  Ar[m][p]
    unsigned short* mp = (unsigned short*)(ws + WS_MP);
    for (int i = t; i < 8 * 16 * 32; i += 256) {
        int ct = i >> 9, rem = i & 511;
        int jl = rem >> 5, k = rem & 31;
        unsigned short v = 0;
        if (k < 16) {
            int j = ct * 16 + jl, m = j >> 1, s = j & 1;
            int p = k >> 1, u = k & 1;
            float Ar = sA[m * 16 + 2 * p], Ai = sA[m * 16 + 2 * p + 1];
            float val = (s == 0) ? ((u == 0) ? Ar : -Ai)
                                 : ((u == 0) ? Ai :  Ar);
            v = f2bf(val);
        }
        mp[i] = v;
    }
    unsigned short* w1p = (unsigned short*)(ws + WS_W1);
    for (int i = t; i < 128 * 32; i += 256) {
        int row = i >> 5, k = i & 31;
        int ct = row >> 4, p = row & 15;
        w1p[i] = (k < 16) ? f2bf(W1[k * 128 + sigma_perm(ct, p)]) : (unsigned short)0;
    }
    unsigned short* w2p = (unsigned short*)(ws + WS_W2);
    for (int i = t; i < 128 * 128; i += 256) {
        int row = i >> 7, k = i & 127;
        int ct = row >> 4, p = row & 15;
        w2p[i] = f2bf(W2[k * 128 + sigma_perm(ct, p)]);
    }
    unsigned short* w3t = (unsigned short*)(ws + WS_W3);
    for (int i = t; i < 16 * 128; i += 256) {
        int col = i >> 7, k = i & 127;
        w3t[i] = f2bf(W3[k * 64 + col]);
    }
}

// ---------------------------------------------------------------------------
// Kernel A: LS gather, 4 threads/element (2 pilots each). 2048 blocks,
// fully-coalesced 16B stores.
// ---------------------------------------------------------------------------
__global__ __launch_bounds__(256) void ce_ls(
    const float* __restrict__ Y, const float* __restrict__ Xp,
    const int* __restrict__ pilot_pos,
    float* __restrict__ lsbuf, int B)
{
    long g = (long)blockIdx.x * 256 + threadIdx.x;
    long e = g >> 2;
    int q = (int)(g & 3);
    if (e >= B) return;
    const float* yrow = Y + e * 128;
    float4 x = *(const float4*)(Xp + e * 16 + q * 4);   // c0,d0,c1,d1 (pilots 2q,2q+1)
    float2 y0 = *(const float2*)(yrow + pilot_pos[2 * q] * 2);
    float2 y1 = *(const float2*)(yrow + pilot_pos[2 * q + 1] * 2);
    float inv0 = 1.0f / (x.x * x.x + x.y * x.y);
    float inv1 = 1.0f / (x.z * x.z + x.w * x.w);
    float4 st;
    st.x = (y0.x * x.x + y0.y * x.y) * inv0;
    st.y = (y0.y * x.x - y0.x * x.y) * inv0;
    st.z = (y1.x * x.z + y1.y * x.w) * inv1;
    st.w = (y1.y * x.z - y1.x * x.w) * inv1;
    *(float4*)(lsbuf + e * 16 + q * 4) = st;
}

// ---------------------------------------------------------------------------
// Kernel B: fully register-resident, barrier-free, LDS-free.
// 256 thr = 4 independent waves, 16 elems/wave. 52 MFMA/wave total.
// Epilogue = 8 MFMA with the MP matrix (zero-pad K trick, as L1).
// ---------------------------------------------------------------------------
__global__ __launch_bounds__(256) void ce_mlp(
    const float* __restrict__ lsbuf,
    const float* __restrict__ b1, const float* __restrict__ b2,
    const float* __restrict__ b3,
    const float* __restrict__ est_w, const float* __restrict__ alpha,
    const char* __restrict__ ws,
    float* __restrict__ out, int B)
{
    const unsigned short* w1p = (const unsigned short*)(ws + WS_W1);
    const unsigned short* w2p = (const unsigned short*)(ws + WS_W2);
    const unsigned short* w3t = (const unsigned short*)(ws + WS_W3);
    const unsigned short* mp  = (const unsigned short*)(ws + WS_MP);

    const int t = threadIdx.x;
    const int w = t >> 6, l = t & 63;
    const int m = l & 15, kg = l >> 4;
    long eg = (long)blockIdx.x * 64 + w * 16 + m;
    long egc = (eg < B) ? eg : (long)(B - 1);

    // ---- coalesced ls input (lanes kg<2); keep f32 for comb ----
    short8v xb = {0, 0, 0, 0, 0, 0, 0, 0};
    float lsv[8];
    #pragma unroll
    for (int i = 0; i < 8; ++i) lsv[i] = 0.f;
    if (kg < 2) {
        const float4* lp = (const float4*)(lsbuf + egc * 16 + kg * 8);
        float4 s0 = lp[0], s1 = lp[1];
        lsv[0] = s0.x; lsv[1] = s0.y; lsv[2] = s0.z; lsv[3] = s0.w;
        lsv[4] = s1.x; lsv[5] = s1.y; lsv[6] = s1.z; lsv[7] = s1.w;
        #pragma unroll
        for (int i = 0; i < 8; ++i) xb[i] = (short)f2bf(lsv[i]);
    }

    const f32x4 z4 = {0.f, 0.f, 0.f, 0.f};
    typedef union { unsigned u[4]; short8v v; } pk_t;

    // ---- Layer 1 (8 MFMA) + repack ----
    pk_t h1[4];
    #pragma unroll
    for (int ks = 0; ks < 4; ++ks) {
        #pragma unroll
        for (int half = 0; half < 2; ++half) {
            int ct = 2 * ks + half;
            short8v wf = *(const short8v*)(w1p + (ct * 16 + m) * 32 + kg * 8);
            f32x4 acc = __builtin_amdgcn_mfma_f32_16x16x32_bf16(wf, xb, z4, 0, 0, 0);
            float4 bv = *(const float4*)(b1 + ks * 32 + kg * 8 + half * 4);
            float v0 = fmaxf(acc[0] + bv.x, 0.f), v1 = fmaxf(acc[1] + bv.y, 0.f);
            float v2 = fmaxf(acc[2] + bv.z, 0.f), v3 = fmaxf(acc[3] + bv.w, 0.f);
            h1[ks].u[2 * half]     = pack2bf(v0, v1);
            h1[ks].u[2 * half + 1] = pack2bf(v2, v3);
        }
    }

    // ---- Layer 2 (32 MFMA) ----
    f32x4 acc2[8];
    #pragma unroll
    for (int ct = 0; ct < 8; ++ct) acc2[ct] = z4;
    #pragma unroll
    for (int ks = 0; ks < 4; ++ks) {
        short8v hf = h1[ks].v;
        #pragma unroll
        for (int ct = 0; ct < 8; ++ct) {
            short8v wf = *(const short8v*)(w2p + (ct * 16 + m) * 128 + ks * 32 + kg * 8);
            acc2[ct] = __builtin_amdgcn_mfma_f32_16x16x32_bf16(wf, hf, acc2[ct], 0, 0, 0);
        }
    }

    // ---- repack -> h2 ----
    pk_t h2[4];
    #pragma unroll
    for (int ks = 0; ks < 4; ++ks) {
        #pragma unroll
        for (int half = 0; half < 2; ++half) {
            int ct = 2 * ks + half;
            float4 bv = *(const float4*)(b2 + ks * 32 + kg * 8 + half * 4);
            float v0 = fmaxf(acc2[ct][0] + bv.x, 0.f), v1 = fmaxf(acc2[ct][1] + bv.y, 0.f);
            float v2 = fmaxf(acc2[ct][2] + bv.z, 0.f), v3 = fmaxf(acc2[ct][3] + bv.w, 0.f);
            h2[ks].u[2 * half]     = pack2bf(v0, v1);
            h2[ks].u[2 * half + 1] = pack2bf(v2, v3);
        }
    }

    // ---- Layer 3 (4 MFMA): lane (kg,m) -> o[4kg+r] of element m ----
    f32x4 acc3 = z4;
    #pragma unroll
    for (int ks = 0; ks < 4; ++ks) {
        short8v wf = *(const short8v*)(w3t + m * 128 + ks * 32 + kg * 8);
        acc3 = __builtin_amdgcn_mfma_f32_16x16x32_bf16(wf, h2[ks].v, acc3, 0, 0, 0);
    }

    // ---- comb in-register: lanes kg<2 build v[8] = (cr,ci) pairs ----
    // o_hi[r] = o[8+4kg+r] comes from lane l+32 (kg+2) via shfl_down.
    float o_hi0 = __shfl_down(acc3[0], 32);
    float o_hi1 = __shfl_down(acc3[1], 32);
    float o_hi2 = __shfl_down(acc3[2], 32);
    float o_hi3 = __shfl_down(acc3[3], 32);
    short8v vb = {0, 0, 0, 0, 0, 0, 0, 0};
    {
        float w0 = est_w[0];
        float al = fminf(fmaxf(alpha[0], 0.f), 1.f);
        float oma = 1.0f - al;
        if (kg < 2) {
            float4 b3lo = *(const float4*)(b3 + 4 * kg);       // b3[4kg..4kg+3]
            float4 b3hi = *(const float4*)(b3 + 8 + 4 * kg);   // b3[8+4kg..]
            float blo[4] = { b3lo.x, b3lo.y, b3lo.z, b3lo.w };
            float bhi[4] = { b3hi.x, b3hi.y, b3hi.z, b3hi.w };
            float ohi[4] = { o_hi0, o_hi1, o_hi2, o_hi3 };
            float olo[4] = { acc3[0], acc3[1], acc3[2], acc3[3] };
            #pragma unroll
            for (int r = 0; r < 4; ++r) {
                float cr = al * (lsv[2 * r] * w0)     + oma * fast_tanh(olo[r] + blo[r]);
                float ci = al * (lsv[2 * r + 1] * w0) + oma * fast_tanh(ohi[r] + bhi[r]);
                vb[2 * r]     = (short)f2bf(cr);
                vb[2 * r + 1] = (short)f2bf(ci);
            }
        }
    }

    // ---- epilogue: 8 MFMA with MP; lane writes out[m][ct*16+4kg .. +3] ----
    if (eg < B) {
        float* orow = out + eg * 128;
        #pragma unroll
        for (int ct = 0; ct < 8; ++ct) {
            short8v mf = *(const short8v*)(mp + (ct * 16 + m) * 32 + kg * 8);
            f32x4 accE = __builtin_amdgcn_mfma_f32_16x16x32_bf16(mf, vb, z4, 0, 0, 0);
            float4 st = { accE[0], accE[1], accE[2], accE[3] };
            *(float4*)(orow + ct * 16 + kg * 4) = st;
        }
    }
}

// ---------------------------------------------------------------------------
// Fallback single kernel (R8, proven 93.8 us) for small ws_size.
// ---------------------------------------------------------------------------
__global__ __launch_bounds__(256) void ce_main_fb(
    const float* __restrict__ Y, const float* __restrict__ Xp,
    const int* __restrict__ pilot_pos,
    const float* __restrict__ b1, const float* __restrict__ b2,
    const float* __restrict__ b3,
    const float* __restrict__ est_w, const float* __restrict__ alpha,
    const char* __restrict__ ws,
    float* __restrict__ out, int B)
{
    __shared__ float sLS[64 * 16];
    __shared__ unsigned short sO[64 * 16];
    const unsigned short* w1p = (const unsigned short*)(ws + WS_W1);
    const unsigned short* w2p = (const unsigned short*)(ws + WS_W2);
    const unsigned short* w3t = (const unsigned short*)(ws + WS_W3);
    const float* Amat = (const float*)(ws + WS_A);
    const int t = threadIdx.x;
    const int w = t >> 6, l = t & 63;
    const int m = l & 15, kg = l >> 4;
    const int e_loc = w * 16 + m;
    long eg = (long)blockIdx.x * 64 + e_loc;
    long egc = (eg < B) ? eg : (long)(B - 1);
    short8v xb = {0, 0, 0, 0, 0, 0, 0, 0};
    if (kg < 2) {
        const float* yrow = Y + egc * 128;
        const float4* xr = (const float4*)(Xp + egc * 16 + kg * 8);
        float4 x0 = xr[0], x1 = xr[1];
        int p0 = kg * 4;
        float2 y0 = *(const float2*)(yrow + pilot_pos[p0 + 0] * 2);
        float2 y1 = *(const float2*)(yrow + pilot_pos[p0 + 1] * 2);
        float2 y2 = *(const float2*)(yrow + pilot_pos[p0 + 2] * 2);
        float2 y3 = *(const float2*)(yrow + pilot_pos[p0 + 3] * 2);
        float ls[8], inv;
        inv = 1.0f / (x0.x * x0.x + x0.y * x0.y);
        ls[0] = (y0.x * x0.x + y0.y * x0.y) * inv;
        ls[1] = (y0.y * x0.x - y0.x * x0.y) * inv;
        inv = 1.0f / (x0.z * x0.z + x0.w * x0.w);
        ls[2] = (y1.x * x0.z + y1.y * x0.w) * inv;
        ls[3] = (y1.y * x0.z - y1.x * x0.w) * inv;
        inv = 1.0f / (x1.x * x1.x + x1.y * x1.y);
        ls[4] = (y2.x * x1.x + y2.y * x1.y) * inv;
        ls[5] = (y2.y * x1.x - y2.x * x1.y) * inv;
        inv = 1.0f / (x1.z * x1.z + x1.w * x1.w);
        ls[6] = (y3.x * x1.z + y3.y * x1.w) * inv;
        ls[7] = (y3.y * x1.z - y3.x * x1.w) * inv;
        float4 s0 = { ls[0], ls[1], ls[2], ls[3] };
        float4 s1 = { ls[4], ls[5], ls[6], ls[7] };
        *(float4*)(sLS + e_loc * 16 + kg * 8)     = s0;
        *(float4*)(sLS + e_loc * 16 + kg * 8 + 4) = s1;
        #pragma unroll
        for (int e = 0; e < 8; ++e) xb[e] = (short)f2bf(ls[e]);
    }
    const f32x4 z4 = {0.f, 0.f, 0.f, 0.f};
    typedef union { unsigned u[4]; short8v v; } pk_t;
    pk_t h1[4];
    #pragma unroll
    for (int ks = 0; ks < 4; ++ks) {
        #pragma unroll
        for (int half = 0; half < 2; ++half) {
            int ct = 2 * ks + half;
            short8v wf = *(const short8v*)(w1p + (ct * 16 + m) * 32 + kg * 8);
            f32x4 acc = __builtin_amdgcn_mfma_f32_16x16x32_bf16(wf, xb, z4, 0, 0, 0);
            float4 bv = *(const float4*)(b1 + ks * 32 + kg * 8 + half * 4);
            float v0 = fmaxf(acc[0] + bv.x, 0.f), v1 = fmaxf(acc[1] + bv.y, 0.f);
            float v2 = fmaxf(acc[2] + bv.z, 0.f), v3 = fmaxf(acc[3] + bv.w, 0.f);
            h1[ks].u[2 * half]     = pack2bf(v0, v1);
            h1[ks].u[2 * half + 1] = pack2bf(v2, v3);
        }
    }
    f32x4 acc2[8];
    #pragma unroll
    for (int ct = 0; ct < 8; ++ct) acc2[ct] = z4;
    #pragma unroll
    for (int ks = 0; ks < 4; ++ks) {
        short8v hf = h1[ks].v;
        #pragma unroll
        for (int ct = 0; ct < 8; ++ct) {
            short8v wf = *(const short8v*)(w2p + (ct * 16 + m) * 128 + ks * 32 + kg * 8);
            acc2[ct] = __builtin_amdgcn_mfma_f32_16x16x32_bf16(wf, hf, acc2[ct], 0, 0, 0);
        }
    }
    pk_t h2[4];
    #pragma unroll
    for (int ks = 0; ks < 4; ++ks) {
        #pragma unroll
        for (int half = 0; half < 2; ++half) {
            int ct = 2 * ks + half;
            float4 bv = *(const float4*)(b2 + ks * 32 + kg * 8 + half * 4);
            float v0 = fmaxf(acc2[ct][0] + bv.x, 0.f), v1 = fmaxf(acc2[ct][1] + bv.y, 0.f);
            float v2 = fmaxf(acc2[ct][2] + bv.z, 0.f), v3 = fmaxf(acc2[ct][3] + bv.w, 0.f);
            h2[ks].u[2 * half]     = pack2bf(v0, v1);
            h2[ks].u[2 * half + 1] = pack2bf(v2, v3);
        }
    }
    f32x4 acc3 = z4;
    #pragma unroll
    for (int ks = 0; ks < 4; ++ks) {
        short8v wf = *(const short8v*)(w3t + m * 128 + ks * 32 + kg * 8);
        acc3 = __builtin_amdgcn_mfma_f32_16x16x32_bf16(wf, h2[ks].v, acc3, 0, 0, 0);
    }
    {
        uint2 u = { pack2bf(acc3[0], acc3[1]), pack2bf(acc3[2], acc3[3]) };
        *(uint2*)(sO + e_loc * 16 + kg * 4) = u;
    }
    __syncthreads();
    float w0 = est_w[0];
    float al = fminf(fmaxf(alpha[0], 0.f), 1.f);
    float oma = 1.0f - al;
    {
        int e2 = t >> 2, q = t & 3;
        float* lsp = sLS + e2 * 16 + q * 4;
        float4 lv = *(float4*)lsp;
        const unsigned short* op = sO + e2 * 16;
        float or0 = bf2f(op[2 * q])     + b3[2 * q];
        float or1 = bf2f(op[2 * q + 1]) + b3[2 * q + 1];
        float oi0 = bf2f(op[8 + 2 * q]) + b3[8 + 2 * q];
        float oi1 = bf2f(op[9 + 2 * q]) + b3[9 + 2 * q];
        float4 cb;
        cb.x = al * (lv.x * w0) + oma * fast_tanh(or0);
        cb.y = al * (lv.y * w0) + oma * fast_tanh(oi0);
        cb.z = al * (lv.z * w0) + oma * fast_tanh(or1);
        cb.w = al * (lv.w * w0) + oma * fast_tanh(oi1);
        *(float4*)lsp = cb;
    }
    __syncthreads();
    {
        int j = l & 31, half = l >> 5;
        float Ar[32];
        const float4* ap = (const float4*)(Amat + j * 32);
        #pragma unroll
        for (int q4 = 0; q4 < 8; ++q4) {
            float4 v = ap[q4];
            Ar[4 * q4 + 0] = v.x; Ar[4 * q4 + 1] = v.y;
            Ar[4 * q4 + 2] = v.z; Ar[4 * q4 + 3] = v.w;
        }
        #pragma unroll
        for (int it = 0; it < 8; ++it) {
            int e2 = w * 16 + 2 * it + half;
            long gelem = (long)blockIdx.x * 64 + e2;
            const float* lsp = sLS + e2 * 16;
            float4 C0 = *(const float4*)(lsp + 0), C1 = *(const float4*)(lsp + 4);
            float4 C2 = *(const float4*)(lsp + 8), C3 = *(const float4*)(lsp + 12);
            float cr[8] = { C0.x, C0.z, C1.x, C1.z, C2.x, C2.z, C3.x, C3.z };
            float ci[8] = { C0.y, C0.w, C1.y, C1.w, C2.y, C2.w, C3.y, C3.w };
            float hr0 = 0.f, hi0 = 0.f, hr1 = 0.f, hi1 = 0.f;
            #pragma unroll
            for (int p = 0; p < 8; ++p) {
                float a0r = Ar[2 * p], a0i = Ar[2 * p + 1];
                float a1r = Ar[16 + 2 * p], a1i = Ar[17 + 2 * p];
                hr0 += cr[p] * a0r - ci[p] * a0i;
                hi0 += cr[p] * a0i + ci[p] * a0r;
                hr1 += cr[p] * a1r - ci[p] * a1i;
                hi1 += cr[p] * a1i + ci[p] * a1r;
            }
            if (gelem < B) {
                float4 st = { hr0, hi0, hr1, hi1 };
                *(float4*)(out + gelem * 128 + j * 4) = st;
            }
        }
    }
}

extern "C" void kernel_launch(void* const* d_in, const int* in_sizes, int n_in,
                              void* d_out, int out_size, void* d_ws, size_t ws_size,
                              hipStream_t stream) {
    const float* Y             = (const float*)d_in[0];
    const float* Xp            = (const float*)d_in[1];
    const int*   pilot_pos     = (const int*)d_in[2];
    const float* W1            = (const float*)d_in[3];
    const float* b1            = (const float*)d_in[4];
    const float* W2            = (const float*)d_in[5];
    const float* b2            = (const float*)d_in[6];
    const float* W3            = (const float*)d_in[7];
    const float* b3            = (const float*)d_in[8];
    const float* est_w         = (const float*)d_in[9];
    const float* alpha         = (const float*)d_in[10];
    const float* decay_param   = (const float*)d_in[11];
    const float* window_logits = (const float*)d_in[12];
    float* out = (float*)d_out;
    char* ws = (char*)d_ws;

    int B = in_sizes[0] / 128;

    hipLaunchKernelGGL(ce_prep_kernel, dim3(1), dim3(256), 0, stream,
                       pilot_pos, decay_param, window_logits, W1, W2, W3, ws);

    size_t need = (size_t)WS_LS + (size_t)B * 64;
    if (ws_size >= need) {
        float* lsbuf = (float*)(ws + WS_LS);
        long nth = (long)B * 4;
        hipLaunchKernelGGL(ce_ls, dim3((unsigned)((nth + 255) / 256)), dim3(256), 0, stream,
                           Y, Xp, pilot_pos, lsbuf, B);
        hipLaunchKernelGGL(ce_mlp, dim3((B + 63) / 64), dim3(256), 0, stream,
                           lsbuf, b1, b2, b3, est_w, alpha, ws, out, B);
    } else {
        hipLaunchKernelGGL(ce_main_fb, dim3((B + 63) / 64), dim3(256), 0, stream,
                           Y, Xp, pilot_pos, b1, b2, b3, est_w, alpha,
                           ws, out, B);
    }
}

// Round 11
// 72.489 us; speedup vs baseline: 1.4118x; 1.4118x over previous
//
#include <hip/hip_runtime.h>
#include <math.h>

typedef __attribute__((ext_vector_type(8))) short short8v;   // 8 bf16 bits
typedef __attribute__((ext_vector_type(4))) float f32x4;     // 16x16 MFMA acc

__device__ __forceinline__ unsigned short f2bf(float x) {
    union { float f; unsigned u; } v; v.f = x;
    unsigned r = v.u + 0x7FFF + ((v.u >> 16) & 1);   // RNE
    return (unsigned short)(r >> 16);
}
__device__ __forceinline__ unsigned pack2bf(float a, float b) {
    return (unsigned)f2bf(a) | ((unsigned)f2bf(b) << 16);
}
__device__ __forceinline__ float fast_tanh(float x) {
    float e = __expf(2.0f * x);
    return 1.0f - 2.0f / (e + 1.0f);
}
__device__ __host__ __forceinline__ int sigma_perm(int ct, int p) {
    return 32 * (ct >> 1) + 8 * (p >> 2) + 4 * (ct & 1) + (p & 3);
}

// d_ws layout (bytes):
//   [0, 4096)       A     f32  [64][16]   (MP source; kept for debugging)
//   [4096, 12288)   W1P   bf16 [8 ct][16 row][32 k]  k>=16 ZERO, sigma rows
//   [12288, 45056)  W2P   bf16 [8 ct][16 row][128 k] sigma rows
//   [45056, 49152)  W3T   bf16 [16 col][128 k]
//   [49152, 57344)  MP    bf16 [8 ct][16 row][32 k]  k>=16 ZERO
#define WS_A    0
#define WS_W1   4096
#define WS_W2   12288
#define WS_W3   45056
#define WS_MP   49152

// ---------------------------------------------------------------------------
// Prep: 65 blocks. Block 0: A + MP + W1P + W3T. Blocks 1..64: W2P (256 ea).
// A/MP/W1P/W3T/W2P builds byte-identical to R10 (proven, absmax 0.0078).
// ---------------------------------------------------------------------------
__global__ __launch_bounds__(256) void ce_prep_kernel(
    const int* __restrict__ pilot_pos,
    const float* __restrict__ decay_param,
    const float* __restrict__ window_logits,
    const float* __restrict__ W1, const float* __restrict__ W2,
    const float* __restrict__ W3,
    char* __restrict__ ws)
{
    int t = threadIdx.x;
    if (blockIdx.x != 0) {
        int i = (int)(blockIdx.x - 1) * 256 + t;         // [0,16384)
        int row = i >> 7, k = i & 127;
        int ct = row >> 4, p = row & 15;
        unsigned short* w2p = (unsigned short*)(ws + WS_W2);
        w2p[i] = f2bf(W2[k * 128 + sigma_perm(ct, p)]);
        return;
    }
    __shared__ float win[8], Gr[64], Gi[64], wln[64], wrn[64];
    __shared__ int lefts[64], pos[8];
    __shared__ float sA[64 * 16];
    if (t < 8) {
        pos[t] = pilot_pos[t];
        win[t] = 1.0f / (1.0f + expf(-window_logits[t]));
    }
    __syncthreads();
    float decay = log1pf(expf(decay_param[0]));
    if (t < 64) {
        float gr = 0.f, gi = 0.f;
        #pragma unroll
        for (int n = 0; n < 8; ++n) {
            float ang = 6.283185307179586f * (float)(n * t) * (1.0f / 64.0f);
            gr += win[n] * cosf(ang);
            gi += win[n] * sinf(ang);
        }
        Gr[t] = gr * (1.0f / 64.0f);
        Gi[t] = gi * (1.0f / 64.0f);
        int lft = 0;
        #pragma unroll
        for (int p = 1; p < 8; ++p) if (pos[p] <= t) lft = p;
        if (lft > 6) lft = 6;
        float x0 = (float)pos[lft], x1 = (float)pos[lft + 1], fi = (float)t;
        float wl = expf(-decay * fabsf(fi - x0));
        float wr = expf(-decay * fabsf(x1 - fi));
        float wsum = wl + wr + 1e-12f;
        lefts[t] = lft; wln[t] = wl / wsum; wrn[t] = wr / wsum;
    }
    __syncthreads();
    if (t < 64) {
        float ar[8], ai[8];
        for (int p = 0; p < 8; ++p) { ar[p] = 0.f; ai[p] = 0.f; }
        for (int i = 0; i < 64; ++i) {
            int d = (i - t) & 63;
            float gr = Gr[d], gi = Gi[d];
            int lft = lefts[i];
            float wa = wln[i], wb = wrn[i];
            ar[lft]     += wa * gr;  ai[lft]     += wa * gi;
            ar[lft + 1] += wb * gr;  ai[lft + 1] += wb * gi;
        }
        float* A = (float*)(ws + WS_A);
        for (int p = 0; p < 8; ++p) {
            A[t * 16 + 2 * p]     = ar[p];
            A[t * 16 + 2 * p + 1] = ai[p];
            sA[t * 16 + 2 * p]     = ar[p];
            sA[t * 16 + 2 * p + 1] = ai[p];
        }
    }
    __syncthreads();
    unsigned short* mp = (unsigned short*)(ws + WS_MP);
    for (int i = t; i < 8 * 16 * 32; i += 256) {
        int ct = i >> 9, rem = i & 511;
        int jl = rem >> 5, k = rem & 31;
        unsigned short v = 0;
        if (k < 16) {
            int j = ct * 16 + jl, m = j >> 1, s = j & 1;
            int p = k >> 1, u = k & 1;
            float Ar = sA[m * 16 + 2 * p], Ai = sA[m * 16 + 2 * p + 1];
            float val = (s == 0) ? ((u == 0) ? Ar : -Ai)
                                 : ((u == 0) ? Ai :  Ar);
            v = f2bf(val);
        }
        mp[i] = v;
    }
    unsigned short* w1p = (unsigned short*)(ws + WS_W1);
    for (int i = t; i < 128 * 32; i += 256) {
        int row = i >> 5, k = i & 31;
        int ct = row >> 4, p = row & 15;
        w1p[i] = (k < 16) ? f2bf(W1[k * 128 + sigma_perm(ct, p)]) : (unsigned short)0;
    }
    unsigned short* w3t = (unsigned short*)(ws + WS_W3);
    for (int i = t; i < 16 * 128; i += 256) {
        int col = i >> 7, k = i & 127;
        w3t[i] = f2bf(W3[k * 64 + col]);
    }
}

// ---------------------------------------------------------------------------
// Fused kernel: gather + MLP + comb + epilogue, ONE kernel, zero LDS,
// zero barriers. 256 thr = 4 independent waves; 32 elems/wave (dual tile,
// each weight fragment load feeds 2 MFMAs). 120 MFMA/wave.
// Lane (kg,m): tl=kg>>1 (tile), pg=kg&1 (pilot group). Gather: all lanes.
//   xb_t0 = own ls (lanes kg<2 valid; kg>=2 garbage x W1P-zero-k = 0)
//   xb_t1 = shfl_xor(xb, 32)      (R7-proven)
// comb: low lanes finish T0, high lanes finish T1 via one shfl_xor of acc3.
// Epilogue MP-MFMA (R10-proven) for both tiles; vb_t1 = shfl_xor(myv,32).
// ---------------------------------------------------------------------------
__global__ __launch_bounds__(256) void ce_fused(
    const float* __restrict__ Y, const float* __restrict__ Xp,
    const int* __restrict__ pilot_pos,
    const float* __restrict__ b1, const float* __restrict__ b2,
    const float* __restrict__ b3,
    const float* __restrict__ est_w, const float* __restrict__ alpha,
    const char* __restrict__ ws,
    float* __restrict__ out, int B)
{
    const unsigned short* w1p = (const unsigned short*)(ws + WS_W1);
    const unsigned short* w2p = (const unsigned short*)(ws + WS_W2);
    const unsigned short* w3t = (const unsigned short*)(ws + WS_W3);
    const unsigned short* mp  = (const unsigned short*)(ws + WS_MP);

    const int t = threadIdx.x;
    const int w = t >> 6, l = t & 63;
    const int m = l & 15, kg = l >> 4;
    const int tl = kg >> 1, pg = kg & 1;
    const long base = (long)blockIdx.x * 128 + w * 32;

    // ---- gather + LS: all 64 lanes; lane serves tile tl, pilots [4pg,4pg+4)
    long e_g = base + tl * 16 + m;
    long e_gc = (e_g < B) ? e_g : (long)(B - 1);
    float lsv[8];
    short8v xb;
    {
        const float* yrow = Y + e_gc * 128;
        const float4* xr = (const float4*)(Xp + e_gc * 16 + pg * 8);
        float4 x0 = xr[0], x1 = xr[1];
        int p0 = pg * 4;
        float2 y0 = *(const float2*)(yrow + pilot_pos[p0 + 0] * 2);
        float2 y1 = *(const float2*)(yrow + pilot_pos[p0 + 1] * 2);
        float2 y2 = *(const float2*)(yrow + pilot_pos[p0 + 2] * 2);
        float2 y3 = *(const float2*)(yrow + pilot_pos[p0 + 3] * 2);
        float inv;
        inv = 1.0f / (x0.x * x0.x + x0.y * x0.y);
        lsv[0] = (y0.x * x0.x + y0.y * x0.y) * inv;
        lsv[1] = (y0.y * x0.x - y0.x * x0.y) * inv;
        inv = 1.0f / (x0.z * x0.z + x0.w * x0.w);
        lsv[2] = (y1.x * x0.z + y1.y * x0.w) * inv;
        lsv[3] = (y1.y * x0.z - y1.x * x0.w) * inv;
        inv = 1.0f / (x1.x * x1.x + x1.y * x1.y);
        lsv[4] = (y2.x * x1.x + y2.y * x1.y) * inv;
        lsv[5] = (y2.y * x1.x - y2.x * x1.y) * inv;
        inv = 1.0f / (x1.z * x1.z + x1.w * x1.w);
        lsv[6] = (y3.x * x1.z + y3.y * x1.w) * inv;
        lsv[7] = (y3.y * x1.z - y3.x * x1.w) * inv;
        #pragma unroll
        for (int e = 0; e < 8; ++e) xb[e] = (short)f2bf(lsv[e]);
    }
    short8v xb1;
    {
        union { short8v v; int i[4]; } ua, ub;
        ua.v = xb;
        #pragma unroll
        for (int q = 0; q < 4; ++q) ub.i[q] = __shfl_xor(ua.i[q], 32);
        xb1 = ub.v;
    }

    const f32x4 z4 = {0.f, 0.f, 0.f, 0.f};
    typedef union { unsigned u[4]; short8v v; } pk_t;

    // ---- Layer 1: 8 weight loads -> 16 MFMA (both tiles) ----
    pk_t h1a[4], h1b[4];
    #pragma unroll
    for (int ks = 0; ks < 4; ++ks) {
        #pragma unroll
        for (int half = 0; half < 2; ++half) {
            int ct = 2 * ks + half;
            short8v wf = *(const short8v*)(w1p + (ct * 16 + m) * 32 + kg * 8);
            f32x4 aA = __builtin_amdgcn_mfma_f32_16x16x32_bf16(wf, xb,  z4, 0, 0, 0);
            f32x4 aB = __builtin_amdgcn_mfma_f32_16x16x32_bf16(wf, xb1, z4, 0, 0, 0);
            float4 bv = *(const float4*)(b1 + ks * 32 + kg * 8 + half * 4);
            h1a[ks].u[2 * half]     = pack2bf(fmaxf(aA[0] + bv.x, 0.f), fmaxf(aA[1] + bv.y, 0.f));
            h1a[ks].u[2 * half + 1] = pack2bf(fmaxf(aA[2] + bv.z, 0.f), fmaxf(aA[3] + bv.w, 0.f));
            h1b[ks].u[2 * half]     = pack2bf(fmaxf(aB[0] + bv.x, 0.f), fmaxf(aB[1] + bv.y, 0.f));
            h1b[ks].u[2 * half + 1] = pack2bf(fmaxf(aB[2] + bv.z, 0.f), fmaxf(aB[3] + bv.w, 0.f));
        }
    }

    // ---- Layer 2: 32 weight loads -> 64 MFMA ----
    f32x4 a2a[8], a2b[8];
    #pragma unroll
    for (int ct = 0; ct < 8; ++ct) { a2a[ct] = z4; a2b[ct] = z4; }
    #pragma unroll
    for (int ks = 0; ks < 4; ++ks) {
        short8v hfa = h1a[ks].v, hfb = h1b[ks].v;
        #pragma unroll
        for (int ct = 0; ct < 8; ++ct) {
            short8v wf = *(const short8v*)(w2p + (ct * 16 + m) * 128 + ks * 32 + kg * 8);
            a2a[ct] = __builtin_amdgcn_mfma_f32_16x16x32_bf16(wf, hfa, a2a[ct], 0, 0, 0);
            a2b[ct] = __builtin_amdgcn_mfma_f32_16x16x32_bf16(wf, hfb, a2b[ct], 0, 0, 0);
        }
    }

    // ---- repack -> h2 (bias loads shared) ----
    pk_t h2a[4], h2b[4];
    #pragma unroll
    for (int ks = 0; ks < 4; ++ks) {
        #pragma unroll
        for (int half = 0; half < 2; ++half) {
            int ct = 2 * ks + half;
            float4 bv = *(const float4*)(b2 + ks * 32 + kg * 8 + half * 4);
            h2a[ks].u[2 * half]     = pack2bf(fmaxf(a2a[ct][0] + bv.x, 0.f), fmaxf(a2a[ct][1] + bv.y, 0.f));
            h2a[ks].u[2 * half + 1] = pack2bf(fmaxf(a2a[ct][2] + bv.z, 0.f), fmaxf(a2a[ct][3] + bv.w, 0.f));
            h2b[ks].u[2 * half]     = pack2bf(fmaxf(a2b[ct][0] + bv.x, 0.f), fmaxf(a2b[ct][1] + bv.y, 0.f));
            h2b[ks].u[2 * half + 1] = pack2bf(fmaxf(a2b[ct][2] + bv.z, 0.f), fmaxf(a2b[ct][3] + bv.w, 0.f));
        }
    }

    // ---- Layer 3: 4 weight loads -> 8 MFMA ----
    f32x4 acc3a = z4, acc3b = z4;
    #pragma unroll
    for (int ks = 0; ks < 4; ++ks) {
        short8v wf = *(const short8v*)(w3t + m * 128 + ks * 32 + kg * 8);
        acc3a = __builtin_amdgcn_mfma_f32_16x16x32_bf16(wf, h2a[ks].v, acc3a, 0, 0, 0);
        acc3b = __builtin_amdgcn_mfma_f32_16x16x32_bf16(wf, h2b[ks].v, acc3b, 0, 0, 0);
    }

    // ---- comb, all 64 lanes. My tile: T0 if kg<2 else T1; pair p = 4*pg+r.
    //  o_low[r]  = o_mytile[4*pg+r]   : own acc3 (low) / partner acc3b (high)
    //  o_high[r] = o_mytile[8+4*pg+r] : partner acc3a (low) / own acc3b (high)
    pk_t myv;
    {
        float w0 = est_w[0];
        float al = fminf(fmaxf(alpha[0], 0.f), 1.f);
        float oma = 1.0f - al;
        float4 b3lo = *(const float4*)(b3 + 4 * pg);
        float4 b3hi = *(const float4*)(b3 + 8 + 4 * pg);
        float blo[4] = { b3lo.x, b3lo.y, b3lo.z, b3lo.w };
        float bhi[4] = { b3hi.x, b3hi.y, b3hi.z, b3hi.w };
        bool low = (kg < 2);
        #pragma unroll
        for (int r = 0; r < 4; ++r) {
            float s0 = __shfl_xor(acc3a[r], 32);
            float s1 = __shfl_xor(acc3b[r], 32);
            float olow  = low ? acc3a[r] : s1;
            float ohigh = low ? s0 : acc3b[r];
            float cr = al * (lsv[2 * r] * w0)     + oma * fast_tanh(olow + blo[r]);
            float ci = al * (lsv[2 * r + 1] * w0) + oma * fast_tanh(ohigh + bhi[r]);
            myv.u[r] = pack2bf(cr, ci);
        }
    }
    // vb for T0: lanes kg<2 hold v_t0[8kg..8kg+8) = own myv (MP k>=16 zero).
    // vb for T1: lanes kg<2 need partner's myv.
    short8v vb0 = myv.v;
    short8v vb1;
    {
        union { short8v v; int i[4]; } ua, ub;
        ua.v = myv.v;
        #pragma unroll
        for (int q = 0; q < 4; ++q) ub.i[q] = __shfl_xor(ua.i[q], 32);
        vb1 = ub.v;
    }

    // ---- epilogue: 8 MP loads -> 16 MFMA, 16 float4 stores ----
    long e0 = base + m, e1 = base + 16 + m;
    float* orow0 = out + e0 * 128;
    float* orow1 = out + e1 * 128;
    #pragma unroll
    for (int ct = 0; ct < 8; ++ct) {
        short8v mf = *(const short8v*)(mp + (ct * 16 + m) * 32 + kg * 8);
        f32x4 eA = __builtin_amdgcn_mfma_f32_16x16x32_bf16(mf, vb0, z4, 0, 0, 0);
        f32x4 eB = __builtin_amdgcn_mfma_f32_16x16x32_bf16(mf, vb1, z4, 0, 0, 0);
        if (e0 < B) {
            float4 st = { eA[0], eA[1], eA[2], eA[3] };
            *(float4*)(orow0 + ct * 16 + kg * 4) = st;
        }
        if (e1 < B) {
            float4 st = { eB[0], eB[1], eB[2], eB[3] };
            *(float4*)(orow1 + ct * 16 + kg * 4) = st;
        }
    }
}

extern "C" void kernel_launch(void* const* d_in, const int* in_sizes, int n_in,
                              void* d_out, int out_size, void* d_ws, size_t ws_size,
                              hipStream_t stream) {
    const float* Y             = (const float*)d_in[0];
    const float* Xp            = (const float*)d_in[1];
    const int*   pilot_pos     = (const int*)d_in[2];
    const float* W1            = (const float*)d_in[3];
    const float* b1            = (const float*)d_in[4];
    const float* W2            = (const float*)d_in[5];
    const float* b2            = (const float*)d_in[6];
    const float* W3            = (const float*)d_in[7];
    const float* b3            = (const float*)d_in[8];
    const float* est_w         = (const float*)d_in[9];
    const float* alpha         = (const float*)d_in[10];
    const float* decay_param   = (const float*)d_in[11];
    const float* window_logits = (const float*)d_in[12];
    float* out = (float*)d_out;
    char* ws = (char*)d_ws;

    int B = in_sizes[0] / 128;

    hipLaunchKernelGGL(ce_prep_kernel, dim3(65), dim3(256), 0, stream,
                       pilot_pos, decay_param, window_logits, W1, W2, W3, ws);
    int grid = (B + 127) / 128;
    hipLaunchKernelGGL(ce_fused, dim3(grid), dim3(256), 0, stream,
                       Y, Xp, pilot_pos, b1, b2, b3, est_w, alpha,
                       ws, out, B);
}